// Round 4
// baseline (522.490 us; speedup 1.0000x reference)
//
#include <hip/hip_runtime.h>
#include <hip/hip_bf16.h>

typedef unsigned short u16;
typedef __attribute__((ext_vector_type(8))) short bf16x8;    // 8 bf16 in 4 VGPRs
typedef __attribute__((ext_vector_type(16))) float f32x16;

static __device__ __forceinline__ u16 f2bf(float f) {
    unsigned u = __float_as_uint(f);
    unsigned r = (u + 0x7fffu + ((u >> 16) & 1u)) >> 16;   // RNE
    return (u16)r;
}
static __device__ __forceinline__ float bf2f(u16 u) {
    return __uint_as_float(((unsigned)u) << 16);
}

static __device__ __forceinline__ void async_copy16(const void* gptr, void* lptr) {
    __builtin_amdgcn_global_load_lds(
        (const __attribute__((address_space(1))) void*)gptr,
        (__attribute__((address_space(3))) void*)lptr, 16, 0, 0);
}

// ---------------------------------------------------------------------------
// fp32 -> bf16 conversion, 4 elems / thread
// ---------------------------------------------------------------------------
__global__ __launch_bounds__(256)
void cvt_f32_bf16(const float* __restrict__ in, u16* __restrict__ out) {
    long i = ((long)blockIdx.x * 256 + threadIdx.x) * 4;
    float4 f = *(const float4*)(in + i);
    u16 o[4] = { f2bf(f.x), f2bf(f.y), f2bf(f.z), f2bf(f.w) };
    *(uint2*)(out + i) = *(const uint2*)o;
}

// ---------------------------------------------------------------------------
// C[m,n] = sum_k A[m,k] * B[n,k]   (row-major, K contiguous — "BT" gemm)
//
// 256x128 block tile, BK=32, 256 threads = 4 waves (2x2), wave-tile 128x64
// as 4x2 of 32x32x16 bf16 MFMA.
//
// R4: SOFTWARE PIPELINE (1-iter lookahead, double-buffered LDS). Iter order:
//     __syncthreads()            // drains tile-k loads — issued a full iter
//                                // ago (~600 cyc of compute), so ~free
//     issue loads(k+1) -> buf[(k+1)&1]   // overwrite safe: all waves' reads
//                                // of that buf retired before the barrier
//     frag reads + MFMA from buf[k&1]
// This removes the exposed global->LDS latency that capped R3 at 38% MfmaUtil
// (R3 issued and consumed a tile inside the same barrier pair).
//
// LDS XOR swizzle: physical 16B slot s of row r holds logical chunk s^(r&3);
// applied on the GLOBAL source address at staging (global_load_lds demands
// linear lane*16B LDS dests); fragment reads un-swizzle with the same XOR.
//
// XCD panel swizzle: flat id % 8 -> XCD-private column panel (L2 locality).
// M mult of 256, N mult of 128, K mult of 32, gridDim.x mult of 8.
// ---------------------------------------------------------------------------
template<bool BF16_OUT>
__global__ __launch_bounds__(256, 2)
void gemm_bt(const u16* __restrict__ A, const u16* __restrict__ B,
             void* __restrict__ Cout, int M, int N, int K) {
    __shared__ __align__(16) u16 As[2][256 * 32];   // 2 x 16 KB
    __shared__ __align__(16) u16 Bs[2][128 * 32];   // 2 x  8 KB

    const int t    = threadIdx.x;
    const int wave = t >> 6;
    const int lane = t & 63;
    const int wm   = (wave >> 1) * 128;    // wave subtile row offset (0/128)
    const int wn   = (wave & 1) * 64;      // wave subtile col offset (0/64)
    const int half = lane >> 5;            // k-half selector (and C-row bit)
    const int l32  = lane & 31;

    // XCD-aware panel remap
    const int id   = blockIdx.y * gridDim.x + blockIdx.x;
    const int cpx  = gridDim.x >> 3;            // columns per XCD
    const int xcd  = id & 7;
    const int loc  = id >> 3;
    const int bx   = xcd * cpx + (loc % cpx);
    const int by   = loc / cpx;

    const int rowA = by * 256;             // M tile
    const int rowB = bx * 128;             // N tile

    // staging: thread t covers row (t>>2) within each 64-row group, physical
    // slot t&3 <- global chunk (t&3)^(row&3)  (XOR swizzle on global side)
    const int ar = t >> 2;                 // 0..63
    const int ac = ((t & 3) ^ (ar & 3)) * 8;
    const u16* Ag[4]; const u16* Bg[2];
#pragma unroll
    for (int i = 0; i < 4; i++) Ag[i] = A + (long)(rowA + i * 64 + ar) * K + ac;
#pragma unroll
    for (int i = 0; i < 2; i++) Bg[i] = B + (long)(rowB + i * 64 + ar) * K + ac;

    f32x16 acc[4][2] = {};

    const int nIter = K >> 5;

    // prologue: tile 0 -> buf 0
#pragma unroll
    for (int i = 0; i < 4; i++) async_copy16(Ag[i], &As[0][i * 2048 + t * 8]);
#pragma unroll
    for (int i = 0; i < 2; i++) async_copy16(Bg[i], &Bs[0][i * 2048 + t * 8]);

    for (int k = 0; k < nIter; k++) {
        __syncthreads();                   // tile-k loads are ~1 iter old: cheap
        const int kn = k + 1;
        if (kn < nIter) {                  // uniform branch
            const int nb = kn & 1;
#pragma unroll
            for (int i = 0; i < 4; i++)
                async_copy16(Ag[i] + kn * 32, &As[nb][i * 2048 + t * 8]);
#pragma unroll
            for (int i = 0; i < 2; i++)
                async_copy16(Bg[i] + kn * 32, &Bs[nb][i * 2048 + t * 8]);
        }

        const u16* asb = As[k & 1];
        const u16* bsb = Bs[k & 1];

        // fragments: lane holds X[r = l32][k = half*8 + j] of K16 slice ks;
        // logical chunk kc = ks*2 + half, un-swizzled with ^(row&3).
        bf16x8 af[4][2], bg[2][2];
#pragma unroll
        for (int mi = 0; mi < 4; mi++)
#pragma unroll
            for (int ks = 0; ks < 2; ks++) {
                int row = wm + mi * 32 + l32;
                af[mi][ks] = *(const bf16x8*)(
                    asb + row * 32 + (((ks * 2 + half) ^ (row & 3)) * 8));
            }
#pragma unroll
        for (int nj = 0; nj < 2; nj++)
#pragma unroll
            for (int ks = 0; ks < 2; ks++) {
                int row = wn + nj * 32 + l32;
                bg[nj][ks] = *(const bf16x8*)(
                    bsb + row * 32 + (((ks * 2 + half) ^ (row & 3)) * 8));
            }
#pragma unroll
        for (int ks = 0; ks < 2; ks++)
#pragma unroll
            for (int mi = 0; mi < 4; mi++)
#pragma unroll
                for (int nj = 0; nj < 2; nj++)
                    acc[mi][nj] = __builtin_amdgcn_mfma_f32_32x32x16_bf16(
                        af[mi][ks], bg[nj][ks], acc[mi][nj], 0, 0, 0);
    }

    // epilogue: 32x32 C/D layout col=lane&31, row=(r&3)+8*(r>>2)+4*half
#pragma unroll
    for (int mi = 0; mi < 4; mi++) {
#pragma unroll
        for (int nj = 0; nj < 2; nj++) {
#pragma unroll
            for (int r = 0; r < 16; r++) {
                int rowt = (r & 3) + 8 * (r >> 2) + 4 * half;
                long m = rowA + wm + mi * 32 + rowt;
                long n = rowB + wn + nj * 32 + l32;
                float v = acc[mi][nj][r];
                if (BF16_OUT) ((u16*)Cout)[m * N + n] = f2bf(v);
                else          ((float*)Cout)[m * N + n] = v;
            }
        }
    }
}

// ---------------------------------------------------------------------------
// Fused Bx-product + depthwise causal conv(L=3) + C-gate.
// BCx: (8192, 6144) bf16 rows = [B(0:2048) | C(2048:4096) | x(4096:6144)]
// y[s,h] = C[s,h] * ( w[h,0]*Bx[s-2,h] + w[h,1]*Bx[s-1,h] + w[h,2]*Bx[s,h] )
// batch boundary: s resets every 4096 rows (zero left-pad per batch)
// ---------------------------------------------------------------------------
union U16x8 { uint4 v; u16 u[8]; };

__global__ __launch_bounds__(256)
void conv_fuse(const u16* __restrict__ BCx, const float* __restrict__ cw,
               u16* __restrict__ y) {
    const int row = blockIdx.x;            // 0..8191
    const int h0  = threadIdx.x * 8;       // 256*8 = 2048
    const int sl  = row & 4095;
    const u16* r0 = BCx + (long)row * 6144;

    U16x8 B0, X0, C0, B1, X1, B2, X2;
    B0.v = *(const uint4*)(r0 + h0);
    C0.v = *(const uint4*)(r0 + 2048 + h0);
    X0.v = *(const uint4*)(r0 + 4096 + h0);
    if (sl >= 1) {
        B1.v = *(const uint4*)(r0 - 6144 + h0);
        X1.v = *(const uint4*)(r0 - 6144 + 4096 + h0);
    } else { B1.v = make_uint4(0,0,0,0); X1.v = make_uint4(0,0,0,0); }
    if (sl >= 2) {
        B2.v = *(const uint4*)(r0 - 12288 + h0);
        X2.v = *(const uint4*)(r0 - 12288 + 4096 + h0);
    } else { B2.v = make_uint4(0,0,0,0); X2.v = make_uint4(0,0,0,0); }

    U16x8 o;
#pragma unroll
    for (int i = 0; i < 8; i++) {
        int h = h0 + i;
        float bx0 = bf2f(B0.u[i]) * bf2f(X0.u[i]);   // tap l=2 (current)
        float bx1 = bf2f(B1.u[i]) * bf2f(X1.u[i]);   // tap l=1 (s-1)
        float bx2 = bf2f(B2.u[i]) * bf2f(X2.u[i]);   // tap l=0 (s-2)
        float v = cw[h*3+2] * bx0 + cw[h*3+1] * bx1 + cw[h*3] * bx2;
        o.u[i] = f2bf(v * bf2f(C0.u[i]));
    }
    *(uint4*)(y + (long)row * 2048 + h0) = o.v;
}

// ---------------------------------------------------------------------------
extern "C" void kernel_launch(void* const* d_in, const int* in_sizes, int n_in,
                              void* d_out, int out_size, void* d_ws, size_t ws_size,
                              hipStream_t stream) {
    const float* hs   = (const float*)d_in[0];   // (2,4096,2048)
    const float* Win  = (const float*)d_in[1];   // (6144,2048)
    const float* cw   = (const float*)d_in[2];   // (2048,1,3)
    const float* Wout = (const float*)d_in[3];   // (2048,2048)
    float* out = (float*)d_out;                  // (2,4096,2048) fp32

    char* ws = (char*)d_ws;
    u16* hsb   = (u16*)(ws);                     //  33,554,432 B
    u16* Winb  = (u16*)(ws +  33554432);         //  25,165,824 B
    u16* Woutb = (u16*)(ws +  58720256);         //   8,388,608 B
    u16* bcx   = (u16*)(ws +  67108864);         // 100,663,296 B
    u16* yb    = (u16*)(ws + 167772160);         //  33,554,432 B  (end 201,326,592)

    cvt_f32_bf16<<<16384, 256, 0, stream>>>(hs,   hsb);    // 16.78M elems
    cvt_f32_bf16<<<12288, 256, 0, stream>>>(Win,  Winb);   // 12.58M
    cvt_f32_bf16<<< 4096, 256, 0, stream>>>(Wout, Woutb);  //  4.19M

    // BCx = hs @ Win^T : M=8192, N=6144, K=2048  (grid 48x32 = 1536 blocks)
    gemm_bt<true ><<<dim3(48, 32), 256, 0, stream>>>(hsb, Winb, bcx, 8192, 6144, 2048);

    conv_fuse<<<8192, 256, 0, stream>>>(bcx, cw, yb);

    // out = y @ Wout^T : M=8192, N=2048, K=2048  (grid 16x32 = 512 blocks)
    gemm_bt<false><<<dim3(16, 32), 256, 0, stream>>>(yb, Woutb, out, 8192, 2048, 2048);
}

// Round 5
// 505.032 us; speedup vs baseline: 1.0346x; 1.0346x over previous
//
#include <hip/hip_runtime.h>
#include <hip/hip_bf16.h>

typedef unsigned short u16;
typedef __attribute__((ext_vector_type(8))) short bf16x8;    // 8 bf16 in 4 VGPRs
typedef __attribute__((ext_vector_type(16))) float f32x16;

static __device__ __forceinline__ u16 f2bf(float f) {
    unsigned u = __float_as_uint(f);
    unsigned r = (u + 0x7fffu + ((u >> 16) & 1u)) >> 16;   // RNE
    return (u16)r;
}
static __device__ __forceinline__ float bf2f(u16 u) {
    return __uint_as_float(((unsigned)u) << 16);
}

static __device__ __forceinline__ void async_copy16(const void* gptr, void* lptr) {
    __builtin_amdgcn_global_load_lds(
        (const __attribute__((address_space(1))) void*)gptr,
        (__attribute__((address_space(3))) void*)lptr, 16, 0, 0);
}

// ---------------------------------------------------------------------------
// fp32 -> bf16 for all three inputs in ONE launch (fewer graph-node gaps).
// Block ranges: [0,16384) -> hs (16.78M), [16384,28672) -> Win (12.58M),
// [28672,32768) -> Wout (4.19M). 1024 elems/block.
// ---------------------------------------------------------------------------
__global__ __launch_bounds__(256)
void cvt_all(const float* __restrict__ a, const float* __restrict__ b,
             const float* __restrict__ c,
             u16* __restrict__ oa, u16* __restrict__ ob, u16* __restrict__ oc) {
    int blk = blockIdx.x;
    const float* src; u16* dst; long base;
    if (blk < 16384)      { src = a; dst = oa; base = blk; }
    else if (blk < 28672) { src = b; dst = ob; base = blk - 16384; }
    else                  { src = c; dst = oc; base = blk - 28672; }
    long i = (base * 256 + threadIdx.x) * 4;
    float4 f = *(const float4*)(src + i);
    u16 o[4] = { f2bf(f.x), f2bf(f.y), f2bf(f.z), f2bf(f.w) };
    *(uint2*)(dst + i) = *(const uint2*)o;
}

// ---------------------------------------------------------------------------
// C[m,n] = sum_k A[m,k] * B[n,k]   (row-major, K contiguous — "BT" gemm)
//
// 256x128 block tile, BK=32, 256 threads = 4 waves (2x2), wave-tile 128x64
// as 4x2 of 32x32x16 bf16 MFMA. Single-buffered (R4's dbuf regressed:
// global->LDS writes contend with ds_read for banks; the barrier wait is
// dedicated LDS-write time).
//
// CONFLICT-FREE XOR swizzle (R5 fix): 16B bank-group of (row,slot) is
// (row*4 + slot) mod 8; row*4 mod 8 = 4*(l32&1). R2's slot = kc^(row&3)
// correlated with l32&1 and hit only 4/8 groups (2x conflict, the measured
// 5.66e7 SQ_LDS_BANK_CONFLICT). New: physical slot = kc ^ ((row>>1)&3)
// -> groups over 8 lanes = 4*(l&1) + (kc^((l>>1)&3)) = permutation of 0..7,
// 8 lanes/group = structural minimum. Swizzle applied on the GLOBAL source
// address at staging (global_load_lds demands linear lane*16B LDS dests);
// fragment reads un-swizzle with the same XOR.
//
// XCD panel swizzle: flat id % 8 -> XCD-private column panel (L2 locality).
// M mult of 256, N mult of 128, K mult of 32, gridDim.x mult of 8.
// ---------------------------------------------------------------------------
template<bool BF16_OUT>
__global__ __launch_bounds__(256, 2)
void gemm_bt(const u16* __restrict__ A, const u16* __restrict__ B,
             void* __restrict__ Cout, int M, int N, int K) {
    __shared__ __align__(16) u16 As[256 * 32];   // 16 KB
    __shared__ __align__(16) u16 Bs[128 * 32];   //  8 KB

    const int t    = threadIdx.x;
    const int wave = t >> 6;
    const int lane = t & 63;
    const int wm   = (wave >> 1) * 128;    // wave subtile row offset (0/128)
    const int wn   = (wave & 1) * 64;      // wave subtile col offset (0/64)
    const int half = lane >> 5;            // k-half selector (and C-row bit)
    const int l32  = lane & 31;

    // XCD-aware panel remap
    const int id   = blockIdx.y * gridDim.x + blockIdx.x;
    const int cpx  = gridDim.x >> 3;            // columns per XCD
    const int xcd  = id & 7;
    const int loc  = id >> 3;
    const int bx   = xcd * cpx + (loc % cpx);
    const int by   = loc / cpx;

    const int rowA = by * 256;             // M tile
    const int rowB = bx * 128;             // N tile

    // staging: thread t covers row ar=(t>>2) of each 64-row group; physical
    // slot t&3 holds global chunk kc = (t&3) ^ ((ar>>1)&3)
    const int ar = t >> 2;                 // 0..63
    const int ac = ((t & 3) ^ ((ar >> 1) & 3)) * 8;
    const u16* Ag[4]; const u16* Bg[2];
#pragma unroll
    for (int i = 0; i < 4; i++) Ag[i] = A + (long)(rowA + i * 64 + ar) * K + ac;
#pragma unroll
    for (int i = 0; i < 2; i++) Bg[i] = B + (long)(rowB + i * 64 + ar) * K + ac;
    // LDS dests: strictly linear = wave-uniform base + lane*16B
    u16* Asl[4]; u16* Bsl[2];
#pragma unroll
    for (int i = 0; i < 4; i++) Asl[i] = As + i * 2048 + t * 8;
#pragma unroll
    for (int i = 0; i < 2; i++) Bsl[i] = Bs + i * 2048 + t * 8;

    f32x16 acc[4][2] = {};

    for (int k0 = 0; k0 < K; k0 += 32) {
        __syncthreads();                    // previous tile's reads done
#pragma unroll
        for (int i = 0; i < 4; i++) async_copy16(Ag[i] + k0, Asl[i]);
#pragma unroll
        for (int i = 0; i < 2; i++) async_copy16(Bg[i] + k0, Bsl[i]);
        __syncthreads();                    // drains vmcnt before barrier

        // fragments: lane holds X[r = l32][k = half*8 + j] of K16 slice ks;
        // logical chunk kc = ks*2 + half at physical slot kc ^ ((row>>1)&3).
        bf16x8 af[4][2], bg[2][2];
#pragma unroll
        for (int mi = 0; mi < 4; mi++)
#pragma unroll
            for (int ks = 0; ks < 2; ks++) {
                int row = wm + mi * 32 + l32;
                af[mi][ks] = *(const bf16x8*)(
                    As + row * 32 + (((ks * 2 + half) ^ ((row >> 1) & 3)) * 8));
            }
#pragma unroll
        for (int nj = 0; nj < 2; nj++)
#pragma unroll
            for (int ks = 0; ks < 2; ks++) {
                int row = wn + nj * 32 + l32;
                bg[nj][ks] = *(const bf16x8*)(
                    Bs + row * 32 + (((ks * 2 + half) ^ ((row >> 1) & 3)) * 8));
            }
#pragma unroll
        for (int ks = 0; ks < 2; ks++)
#pragma unroll
            for (int mi = 0; mi < 4; mi++)
#pragma unroll
                for (int nj = 0; nj < 2; nj++)
                    acc[mi][nj] = __builtin_amdgcn_mfma_f32_32x32x16_bf16(
                        af[mi][ks], bg[nj][ks], acc[mi][nj], 0, 0, 0);
    }

    // epilogue: 32x32 C/D layout col=lane&31, row=(r&3)+8*(r>>2)+4*half
#pragma unroll
    for (int mi = 0; mi < 4; mi++) {
#pragma unroll
        for (int nj = 0; nj < 2; nj++) {
#pragma unroll
            for (int r = 0; r < 16; r++) {
                int rowt = (r & 3) + 8 * (r >> 2) + 4 * half;
                long m = rowA + wm + mi * 32 + rowt;
                long n = rowB + wn + nj * 32 + l32;
                float v = acc[mi][nj][r];
                if (BF16_OUT) ((u16*)Cout)[m * N + n] = f2bf(v);
                else          ((float*)Cout)[m * N + n] = v;
            }
        }
    }
}

// ---------------------------------------------------------------------------
// Fused Bx-product + depthwise causal conv(L=3) + C-gate.
// BCx: (8192, 6144) bf16 rows = [B(0:2048) | C(2048:4096) | x(4096:6144)]
// y[s,h] = C[s,h] * ( w[h,0]*Bx[s-2,h] + w[h,1]*Bx[s-1,h] + w[h,2]*Bx[s,h] )
// batch boundary: s resets every 4096 rows (zero left-pad per batch)
// ---------------------------------------------------------------------------
union U16x8 { uint4 v; u16 u[8]; };

__global__ __launch_bounds__(256)
void conv_fuse(const u16* __restrict__ BCx, const float* __restrict__ cw,
               u16* __restrict__ y) {
    const int row = blockIdx.x;            // 0..8191
    const int h0  = threadIdx.x * 8;       // 256*8 = 2048
    const int sl  = row & 4095;
    const u16* r0 = BCx + (long)row * 6144;

    U16x8 B0, X0, C0, B1, X1, B2, X2;
    B0.v = *(const uint4*)(r0 + h0);
    C0.v = *(const uint4*)(r0 + 2048 + h0);
    X0.v = *(const uint4*)(r0 + 4096 + h0);
    if (sl >= 1) {
        B1.v = *(const uint4*)(r0 - 6144 + h0);
        X1.v = *(const uint4*)(r0 - 6144 + 4096 + h0);
    } else { B1.v = make_uint4(0,0,0,0); X1.v = make_uint4(0,0,0,0); }
    if (sl >= 2) {
        B2.v = *(const uint4*)(r0 - 12288 + h0);
        X2.v = *(const uint4*)(r0 - 12288 + 4096 + h0);
    } else { B2.v = make_uint4(0,0,0,0); X2.v = make_uint4(0,0,0,0); }

    U16x8 o;
#pragma unroll
    for (int i = 0; i < 8; i++) {
        int h = h0 + i;
        float bx0 = bf2f(B0.u[i]) * bf2f(X0.u[i]);   // tap l=2 (current)
        float bx1 = bf2f(B1.u[i]) * bf2f(X1.u[i]);   // tap l=1 (s-1)
        float bx2 = bf2f(B2.u[i]) * bf2f(X2.u[i]);   // tap l=0 (s-2)
        float v = cw[h*3+2] * bx0 + cw[h*3+1] * bx1 + cw[h*3] * bx2;
        o.u[i] = f2bf(v * bf2f(C0.u[i]));
    }
    *(uint4*)(y + (long)row * 2048 + h0) = o.v;
}

// ---------------------------------------------------------------------------
extern "C" void kernel_launch(void* const* d_in, const int* in_sizes, int n_in,
                              void* d_out, int out_size, void* d_ws, size_t ws_size,
                              hipStream_t stream) {
    const float* hs   = (const float*)d_in[0];   // (2,4096,2048)
    const float* Win  = (const float*)d_in[1];   // (6144,2048)
    const float* cw   = (const float*)d_in[2];   // (2048,1,3)
    const float* Wout = (const float*)d_in[3];   // (2048,2048)
    float* out = (float*)d_out;                  // (2,4096,2048) fp32

    char* ws = (char*)d_ws;
    u16* hsb   = (u16*)(ws);                     //  33,554,432 B
    u16* Winb  = (u16*)(ws +  33554432);         //  25,165,824 B
    u16* Woutb = (u16*)(ws +  58720256);         //   8,388,608 B
    u16* bcx   = (u16*)(ws +  67108864);         // 100,663,296 B
    u16* yb    = (u16*)(ws + 167772160);         //  33,554,432 B  (end 201,326,592)

    cvt_all<<<32768, 256, 0, stream>>>(hs, Win, Wout, hsb, Winb, Woutb);

    // BCx = hs @ Win^T : M=8192, N=6144, K=2048  (grid 48x32 = 1536 blocks)
    gemm_bt<true ><<<dim3(48, 32), 256, 0, stream>>>(hsb, Winb, bcx, 8192, 6144, 2048);

    conv_fuse<<<8192, 256, 0, stream>>>(bcx, cw, yb);

    // out = y @ Wout^T : M=8192, N=2048, K=2048  (grid 16x32 = 512 blocks)
    gemm_bt<false><<<dim3(16, 32), 256, 0, stream>>>(yb, Woutb, out, 8192, 2048, 2048);
}